// Round 4
// baseline (1206.846 us; speedup 1.0000x reference)
//
#include <hip/hip_runtime.h>

#define B_ 256
#define T_ 1024
#define V_ 5000
#define D_ 100
#define H_ 64
#define C_ 2
#define NE_ 4   // batch elements interleaved per wave (ILP to fill the chain)

typedef float f32x4 __attribute__((ext_vector_type(4)));

// ---------------------------------------------------------------------------
// Kernel 1: EW[v][h] = 2*(sum_d E[v][d] * W[d][h] + b[h])   (unchanged)
// Pre-doubled (exact in fp32) so the RNN's tanh needs e^{x2} with no 2*x mul.
// ---------------------------------------------------------------------------
__global__ __launch_bounds__(256) void ew_kernel(const float* __restrict__ E,
                                                 const float* __restrict__ W,
                                                 const float* __restrict__ bias,
                                                 float* __restrict__ EW) {
    int idx = blockIdx.x * 256 + threadIdx.x;   // 0 .. V_*H_
    if (idx >= V_ * H_) return;
    int h = idx & (H_ - 1);
    int v = idx >> 6;
    float acc = bias[h];
    const float* Erow = E + v * D_;
    #pragma unroll 4
    for (int d = 0; d < D_; ++d) {
        acc = fmaf(Erow[d], W[d * H_ + h], acc);
    }
    EW[idx] = 2.0f * acc;    // x2 fold: exact scaling, bit-identical tanh
}

// ---------------------------------------------------------------------------
// Kernel 2: RNN. R8: FOUR batch elements per wave.
// R4-R7 post-mortem: three different inner loops (LDS-U+readlane, global-U,
// reg-U+LDS-broadcast) ALL ran ~665 cyc/step with VALUBusy 15-17% -- the
// single wave's serial chain (LDS roundtrip + 16-deep FMA + expf) leaves the
// SIMD idle ~70% of every step. Instruction count was never the bottleneck.
// Fix: interleave NE=4 independent recurrences in one instruction stream.
// The 4 chains share register-pinned U and have no cross-deps, so the
// scheduler fills each chain's DS/ALU latency with the others' work.
// Per-element floor moves from 665 cyc (latency) to ~190 cyc (DS throughput:
// 17 DS ops x ~12 cyc). Grid: B/4 = 64 blocks -- fine, we're latency-bound.
// All NE-indexed arrays only touched inside #pragma unroll (no scratch).
// Kept: reg-pinned 2*U (VGPR=132 proved it), LDS h-broadcast, padded sh_tok,
// 2-step EW prefetch, clampless tanh hn = 1 - 2*rcp(e^{x2}+1).
// ---------------------------------------------------------------------------
__global__ __launch_bounds__(64, 1) void rnn_kernel(const int* __restrict__ tokens,
                                                    const float* __restrict__ EW,
                                                    const float* __restrict__ U,
                                                    const float* __restrict__ Wd,
                                                    const float* __restrict__ bd,
                                                    float* __restrict__ out) {
    const int b0 = blockIdx.x * NE_;   // first batch element of this wave
    const int j  = threadIdx.x;        // 0..63 : hidden unit

    __shared__ int   sh_tok[NE_][T_ + 2];   // 16.4 KB (+pad kills tail guard)
    __shared__ float sh_h[NE_][H_];         // 1 KB broadcast buffers

    // --- 2*U column j -> 16 float4 (64 VGPRs). Coalesced across lanes. ---
    f32x4 uq[16];
    #pragma unroll
    for (int c = 0; c < 16; ++c) {
        uq[c][0] = 2.0f * U[(4 * c + 0) * H_ + j];
        uq[c][1] = 2.0f * U[(4 * c + 1) * H_ + j];
        uq[c][2] = 2.0f * U[(4 * c + 2) * H_ + j];
        uq[c][3] = 2.0f * U[(4 * c + 3) * H_ + j];
    }
    // SINGLE pin: all 64 values live in VGPRs at once (R7-verified).
    asm volatile("" : "+v"(uq[0]), "+v"(uq[1]), "+v"(uq[2]), "+v"(uq[3]),
                      "+v"(uq[4]), "+v"(uq[5]), "+v"(uq[6]), "+v"(uq[7]),
                      "+v"(uq[8]), "+v"(uq[9]), "+v"(uq[10]), "+v"(uq[11]),
                      "+v"(uq[12]), "+v"(uq[13]), "+v"(uq[14]), "+v"(uq[15]));

    #pragma unroll
    for (int e = 0; e < NE_; ++e) {
        const int* tok = tokens + (b0 + e) * T_;
        #pragma unroll
        for (int k = 0; k < T_ / H_; ++k) {
            sh_tok[e][k * H_ + j] = tok[k * H_ + j];    // coalesced
        }
        if (j < 2) sh_tok[e][T_ + j] = 0;               // pad
    }
    __syncthreads();

    float h[NE_], pooled[NE_];
    int2  tkA[NE_];
    float xw0[NE_], xw1[NE_];
    #pragma unroll
    for (int e = 0; e < NE_; ++e) {
        h[e] = 0.f;
        pooled[e] = 0.f;
        tkA[e] = *(const int2*)&sh_tok[e][0];
        xw0[e] = EW[tkA[e].x * H_ + j];
        xw1[e] = EW[tkA[e].y * H_ + j];
    }

    // one recurrence step for element e (compile-time e only!)
    #define RNN_STEP(e, tokv, xwv)                                       \
    {                                                                    \
        sh_h[e][j] = h[e];                                               \
        float a0 = (xwv), a1 = 0.f, a2 = 0.f, a3 = 0.f;                  \
        _Pragma("unroll")                                                \
        for (int c = 0; c < 16; ++c) {                                   \
            f32x4 hv = *(const f32x4*)&sh_h[e][4 * c];                   \
            a0 = fmaf(hv[0], uq[c][0], a0);                              \
            a1 = fmaf(hv[1], uq[c][1], a1);                              \
            a2 = fmaf(hv[2], uq[c][2], a2);                              \
            a3 = fmaf(hv[3], uq[c][3], a3);                              \
        }                                                                \
        float x2 = (a0 + a1) + (a2 + a3);                                \
        float ef = __expf(x2);                                           \
        float r = __builtin_amdgcn_rcpf(ef + 1.f);                       \
        float hn = fmaf(-2.f, r, 1.f);                                   \
        h[e] = ((tokv) != 0) ? hn : h[e];                                \
        pooled[e] += h[e];                                               \
    }

    for (int t = 0; t < T_; t += 2) {
        // in-loop pin: any uq spill would force an in-loop reload.
        asm volatile("" :: "v"(uq[0]), "v"(uq[1]), "v"(uq[2]), "v"(uq[3]),
                           "v"(uq[4]), "v"(uq[5]), "v"(uq[6]), "v"(uq[7]),
                           "v"(uq[8]), "v"(uq[9]), "v"(uq[10]), "v"(uq[11]),
                           "v"(uq[12]), "v"(uq[13]), "v"(uq[14]), "v"(uq[15]));

        // prefetch steps t+2, t+3 for all elements (8 loads in flight;
        // pad makes the tail read safe: EW[0])
        int2  tkB[NE_];
        float xw2[NE_], xw3[NE_];
        #pragma unroll
        for (int e = 0; e < NE_; ++e) {
            tkB[e] = *(const int2*)&sh_tok[e][t + 2];
            xw2[e] = EW[tkB[e].x * H_ + j];
            xw3[e] = EW[tkB[e].y * H_ + j];
        }

        // 4 independent chains, adjacent in source -> scheduler interleaves
        #pragma unroll
        for (int e = 0; e < NE_; ++e) RNN_STEP(e, tkA[e].x, xw0[e]);
        #pragma unroll
        for (int e = 0; e < NE_; ++e) RNN_STEP(e, tkA[e].y, xw1[e]);

        #pragma unroll
        for (int e = 0; e < NE_; ++e) {
            tkA[e] = tkB[e];
            xw0[e] = xw2[e];
            xw1[e] = xw3[e];
        }
    }
    #undef RNN_STEP

    // ---- epilogue: pooled mean -> dense(2) -> sigmoid, per element ----
    float wd0 = Wd[j * C_ + 0];
    float wd1 = Wd[j * C_ + 1];
    #pragma unroll
    for (int e = 0; e < NE_; ++e) {
        float p = pooled[e] * (1.0f / (float)T_);
        float v0 = p * wd0;
        float v1 = p * wd1;
        #pragma unroll
        for (int off = 32; off >= 1; off >>= 1) {
            v0 += __shfl_down(v0, off, 64);
            v1 += __shfl_down(v1, off, 64);
        }
        if (j == 0) {
            float l0 = v0 + bd[0];
            float l1 = v1 + bd[1];
            out[(b0 + e) * C_ + 0] = 1.f / (1.f + __expf(-l0));
            out[(b0 + e) * C_ + 1] = 1.f / (1.f + __expf(-l1));
        }
    }
}

// ---------------------------------------------------------------------------
extern "C" void kernel_launch(void* const* d_in, const int* in_sizes, int n_in,
                              void* d_out, int out_size, void* d_ws, size_t ws_size,
                              hipStream_t stream) {
    const int*   tokens = (const int*)  d_in[0];  // [B,T] int32
    const float* E      = (const float*)d_in[1];  // [V,D]
    const float* W      = (const float*)d_in[2];  // [D,H]
    const float* U      = (const float*)d_in[3];  // [H,H]
    const float* bias   = (const float*)d_in[4];  // [H]
    const float* Wd     = (const float*)d_in[5];  // [H,C]
    const float* bd     = (const float*)d_in[6];  // [C]
    float* out = (float*)d_out;                   // [B,C]
    float* EW  = (float*)d_ws;                    // [V,H] scratch: 1.28 MB

    ew_kernel<<<(V_ * H_ + 255) / 256, 256, 0, stream>>>(E, W, bias, EW);
    rnn_kernel<<<B_ / NE_, H_, 0, stream>>>(tokens, EW, U, Wd, bd, out);
}

// Round 5
// 335.430 us; speedup vs baseline: 3.5979x; 3.5979x over previous
//
#include <hip/hip_runtime.h>

#define B_ 256
#define T_ 1024
#define V_ 5000
#define D_ 100
#define H_ 64
#define C_ 2

typedef float f32x4 __attribute__((ext_vector_type(4)));

#define SCALE_ 2.885390081777927f   // 2*log2(e): exp2(SCALE*x) == e^{2x}

// ---------------------------------------------------------------------------
// Kernel 1: EW[v][h] = 2*log2e*(sum_d E[v][d]*W[d][h] + b[h])
// Pre-scaled so the RNN tanh needs a bare v_exp_f32 (no mul on the path).
// ---------------------------------------------------------------------------
__global__ __launch_bounds__(256) void ew_kernel(const float* __restrict__ E,
                                                 const float* __restrict__ W,
                                                 const float* __restrict__ bias,
                                                 float* __restrict__ EW) {
    int idx = blockIdx.x * 256 + threadIdx.x;   // 0 .. V_*H_
    if (idx >= V_ * H_) return;
    int h = idx & (H_ - 1);
    int v = idx >> 6;
    float acc = bias[h];
    const float* Erow = E + v * D_;
    #pragma unroll 4
    for (int d = 0; d < D_; ++d) {
        acc = fmaf(Erow[d], W[d * H_ + h], acc);
    }
    EW[idx] = SCALE_ * acc;
}

// ---------------------------------------------------------------------------
// Kernel 2: RNN, one wave per batch element, 256 blocks (= CU count).
// R8 lesson: wall = 1024 * step_cyc / 2.4GHz regardless of per-wave batching
// (B == #CUs), so the ONLY lever is the single-chain critical path.
// R7 decomposition of the 666-cyc step: ~200 issue + ~460 stall, all stall
// from the LDS h-broadcast round trip (write -> lgkmcnt(0) -> 16 reads) on
// the serial h->h dependency.
// R9: PURE-VALU step. h broadcast by 64 v_readlane (independent, 2cyc each),
// U register-pinned (R7-verified: single multi-operand asm pin, VGPR=132),
// tanh via bare v_exp_f32 (inputs pre-scaled by 2*log2e), NO memory ops on
// the critical path. Expected step ~300-380 cyc (issue-bound).
// Kept: padded sh_tok (ds_read_b64 per 2 steps, off-path), 2-step EW
// prefetch, clampless tanh  hn = 1 - 2*rcp(exp2(s*x)+1)  (inf->1, 0->-1).
// ---------------------------------------------------------------------------
__device__ __forceinline__ float readlane_f(float v, int lane) {
    return __uint_as_float(__builtin_amdgcn_readlane(__float_as_uint(v), lane));
}

__global__ __launch_bounds__(64, 1) void rnn_kernel(const int* __restrict__ tokens,
                                                    const float* __restrict__ EW,
                                                    const float* __restrict__ U,
                                                    const float* __restrict__ Wd,
                                                    const float* __restrict__ bd,
                                                    float* __restrict__ out) {
    const int b = blockIdx.x;     // batch element
    const int j = threadIdx.x;    // 0..63 : hidden unit

    __shared__ int sh_tok[T_ + 2];   // 4 KB + pad (kills tail guard)

    // --- (2*log2e)*U column j -> 16 float4 (64 VGPRs). Coalesced. ---
    f32x4 uq[16];
    #pragma unroll
    for (int c = 0; c < 16; ++c) {
        uq[c][0] = SCALE_ * U[(4 * c + 0) * H_ + j];
        uq[c][1] = SCALE_ * U[(4 * c + 1) * H_ + j];
        uq[c][2] = SCALE_ * U[(4 * c + 2) * H_ + j];
        uq[c][3] = SCALE_ * U[(4 * c + 3) * H_ + j];
    }
    // SINGLE pin: all 64 values live in VGPRs at once (R7-verified).
    asm volatile("" : "+v"(uq[0]), "+v"(uq[1]), "+v"(uq[2]), "+v"(uq[3]),
                      "+v"(uq[4]), "+v"(uq[5]), "+v"(uq[6]), "+v"(uq[7]),
                      "+v"(uq[8]), "+v"(uq[9]), "+v"(uq[10]), "+v"(uq[11]),
                      "+v"(uq[12]), "+v"(uq[13]), "+v"(uq[14]), "+v"(uq[15]));

    const int* tok = tokens + b * T_;
    #pragma unroll
    for (int k = 0; k < T_ / H_; ++k) {
        sh_tok[k * H_ + j] = tok[k * H_ + j];    // coalesced
    }
    if (j < 2) sh_tok[T_ + j] = 0;               // pad
    __syncthreads();

    float h = 0.f;
    float pooled = 0.f;

    // 2-step-deep xw prefetch pipeline (covers L2 latency of EW gather)
    int2 tkA = *(const int2*)&sh_tok[0];
    float xw0 = EW[tkA.x * H_ + j];
    float xw1 = EW[tkA.y * H_ + j];

    // one recurrence step: pure VALU (readlane broadcast + pinned-reg U)
    #define RNN_STEP(tokv, xwv)                                          \
    {                                                                    \
        float a0 = (xwv), a1 = 0.f, a2 = 0.f, a3 = 0.f;                  \
        _Pragma("unroll")                                                \
        for (int c = 0; c < 16; ++c) {                                   \
            a0 = fmaf(readlane_f(h, 4 * c + 0), uq[c][0], a0);           \
            a1 = fmaf(readlane_f(h, 4 * c + 1), uq[c][1], a1);           \
            a2 = fmaf(readlane_f(h, 4 * c + 2), uq[c][2], a2);           \
            a3 = fmaf(readlane_f(h, 4 * c + 3), uq[c][3], a3);           \
        }                                                                \
        float x2 = (a0 + a1) + (a2 + a3);                                \
        float ef = __builtin_amdgcn_exp2f(x2);                           \
        float r = __builtin_amdgcn_rcpf(ef + 1.f);                       \
        float hn = fmaf(-2.f, r, 1.f);                                   \
        h = ((tokv) != 0) ? hn : h;                                      \
        pooled += h;                                                     \
    }

    for (int t = 0; t < T_; t += 2) {
        // in-loop pin: any uq spill would force an in-loop reload.
        asm volatile("" :: "v"(uq[0]), "v"(uq[1]), "v"(uq[2]), "v"(uq[3]),
                           "v"(uq[4]), "v"(uq[5]), "v"(uq[6]), "v"(uq[7]),
                           "v"(uq[8]), "v"(uq[9]), "v"(uq[10]), "v"(uq[11]),
                           "v"(uq[12]), "v"(uq[13]), "v"(uq[14]), "v"(uq[15]));

        // prefetch steps t+2, t+3 (pad makes the tail read safe: EW[0])
        int2 tkB = *(const int2*)&sh_tok[t + 2];
        float xw2 = EW[tkB.x * H_ + j];
        float xw3 = EW[tkB.y * H_ + j];

        RNN_STEP(tkA.x, xw0);
        RNN_STEP(tkA.y, xw1);

        tkA = tkB;
        xw0 = xw2;
        xw1 = xw3;
    }
    #undef RNN_STEP

    // ---- epilogue: pooled mean -> dense(2) -> sigmoid ----
    float p = pooled * (1.0f / (float)T_);
    float v0 = p * Wd[j * C_ + 0];
    float v1 = p * Wd[j * C_ + 1];
    #pragma unroll
    for (int off = 32; off >= 1; off >>= 1) {
        v0 += __shfl_down(v0, off, 64);
        v1 += __shfl_down(v1, off, 64);
    }
    if (j == 0) {
        float l0 = v0 + bd[0];
        float l1 = v1 + bd[1];
        out[b * C_ + 0] = 1.f / (1.f + __expf(-l0));
        out[b * C_ + 1] = 1.f / (1.f + __expf(-l1));
    }
}

// ---------------------------------------------------------------------------
extern "C" void kernel_launch(void* const* d_in, const int* in_sizes, int n_in,
                              void* d_out, int out_size, void* d_ws, size_t ws_size,
                              hipStream_t stream) {
    const int*   tokens = (const int*)  d_in[0];  // [B,T] int32
    const float* E      = (const float*)d_in[1];  // [V,D]
    const float* W      = (const float*)d_in[2];  // [D,H]
    const float* U      = (const float*)d_in[3];  // [H,H]
    const float* bias   = (const float*)d_in[4];  // [H]
    const float* Wd     = (const float*)d_in[5];  // [H,C]
    const float* bd     = (const float*)d_in[6];  // [C]
    float* out = (float*)d_out;                   // [B,C]
    float* EW  = (float*)d_ws;                    // [V,H] scratch: 1.28 MB

    ew_kernel<<<(V_ * H_ + 255) / 256, 256, 0, stream>>>(E, W, bias, EW);
    rnn_kernel<<<B_, H_, 0, stream>>>(tokens, EW, U, Wd, bd, out);
}

// Round 6
// 320.784 us; speedup vs baseline: 3.7622x; 1.0457x over previous
//
#include <hip/hip_runtime.h>

#define B_ 256
#define T_ 1024
#define V_ 5000
#define D_ 100
#define H_ 64
#define C_ 2

typedef float f32x4 __attribute__((ext_vector_type(4)));

#define SCALE_ 2.885390081777927f   // 2*log2(e): exp2(SCALE*x) == e^{2x}

// ---------------------------------------------------------------------------
// Kernel 1: EW[v][h] = 2*log2e*(sum_d E[v][d]*W[d][h] + b[h])   (unchanged)
// ---------------------------------------------------------------------------
__global__ __launch_bounds__(256) void ew_kernel(const float* __restrict__ E,
                                                 const float* __restrict__ W,
                                                 const float* __restrict__ bias,
                                                 float* __restrict__ EW) {
    int idx = blockIdx.x * 256 + threadIdx.x;   // 0 .. V_*H_
    if (idx >= V_ * H_) return;
    int h = idx & (H_ - 1);
    int v = idx >> 6;
    float acc = bias[h];
    const float* Erow = E + v * D_;
    #pragma unroll 4
    for (int d = 0; d < D_; ++d) {
        acc = fmaf(Erow[d], W[d * H_ + h], acc);
    }
    EW[idx] = SCALE_ * acc;
}

// ---------------------------------------------------------------------------
// Kernel 2: RNN, one wave per batch element, 256 blocks (= CU count).
// R9 post-mortem: pure-VALU step ran 623 cyc vs ~300 issue floor; VALUBusy
// 70%-of-SIMD. Diagnosis: v_readlane -> v_fmac emitted as adjacent pairs
// recycling one SGPR => per-pair VALU-writes-SGPR/VALU-reads-SGPR hazard
// (~2-4 cyc) + WAR serialization ~= the whole 300-cyc gap. This was present
// in EVERY readlane variant since R4 -- why U's location never mattered.
// R10: group-of-8 broadcast. 8 readlanes back-to-back into 8 SIMULTANEOUSLY
// LIVE uniform values (8-operand "+s" asm pin forces 8 distinct SGPRs),
// then 8 FMAs. Producer->consumer distance >= 8 insts (~16 cyc) covers the
// hazard; no SGPR recycling. SGPR cost +8 (96 -> ~104, budget ~102-112 ok).
// Kept: reg-pinned SCALE_*U (VGPR=104 proves pin), padded sh_tok, 2-step EW
// prefetch, tanh = 1 - 2*rcp(exp2(SCALE*x)+1) via bare v_exp_f32.
// ---------------------------------------------------------------------------
__device__ __forceinline__ float readlane_f(float v, int lane) {
    return __uint_as_float(__builtin_amdgcn_readlane(__float_as_uint(v), lane));
}

__global__ __launch_bounds__(64, 1) void rnn_kernel(const int* __restrict__ tokens,
                                                    const float* __restrict__ EW,
                                                    const float* __restrict__ U,
                                                    const float* __restrict__ Wd,
                                                    const float* __restrict__ bd,
                                                    float* __restrict__ out) {
    const int b = blockIdx.x;     // batch element
    const int j = threadIdx.x;    // 0..63 : hidden unit

    __shared__ int sh_tok[T_ + 2];   // 4 KB + pad (kills tail guard)

    // --- (2*log2e)*U column j -> 16 float4 (64 VGPRs). Coalesced. ---
    f32x4 uq[16];
    #pragma unroll
    for (int c = 0; c < 16; ++c) {
        uq[c][0] = SCALE_ * U[(4 * c + 0) * H_ + j];
        uq[c][1] = SCALE_ * U[(4 * c + 1) * H_ + j];
        uq[c][2] = SCALE_ * U[(4 * c + 2) * H_ + j];
        uq[c][3] = SCALE_ * U[(4 * c + 3) * H_ + j];
    }
    // SINGLE pin: all 64 values live in VGPRs at once (R7/R9-verified).
    asm volatile("" : "+v"(uq[0]), "+v"(uq[1]), "+v"(uq[2]), "+v"(uq[3]),
                      "+v"(uq[4]), "+v"(uq[5]), "+v"(uq[6]), "+v"(uq[7]),
                      "+v"(uq[8]), "+v"(uq[9]), "+v"(uq[10]), "+v"(uq[11]),
                      "+v"(uq[12]), "+v"(uq[13]), "+v"(uq[14]), "+v"(uq[15]));

    const int* tok = tokens + b * T_;
    #pragma unroll
    for (int k = 0; k < T_ / H_; ++k) {
        sh_tok[k * H_ + j] = tok[k * H_ + j];    // coalesced
    }
    if (j < 2) sh_tok[T_ + j] = 0;               // pad
    __syncthreads();

    float h = 0.f;
    float pooled = 0.f;

    // 2-step-deep xw prefetch pipeline (covers L2 latency of EW gather)
    int2 tkA = *(const int2*)&sh_tok[0];
    float xw0 = EW[tkA.x * H_ + j];
    float xw1 = EW[tkA.y * H_ + j];

    // one group: 8 hazard-free readlanes (distinct SGPRs) then 8 FMAs
    #define DOT_GROUP(g)                                                 \
    {                                                                    \
        float s0 = readlane_f(h, 8 * (g) + 0);                           \
        float s1 = readlane_f(h, 8 * (g) + 1);                           \
        float s2 = readlane_f(h, 8 * (g) + 2);                           \
        float s3 = readlane_f(h, 8 * (g) + 3);                           \
        float s4 = readlane_f(h, 8 * (g) + 4);                           \
        float s5 = readlane_f(h, 8 * (g) + 5);                           \
        float s6 = readlane_f(h, 8 * (g) + 6);                           \
        float s7 = readlane_f(h, 8 * (g) + 7);                           \
        asm volatile("" : "+s"(s0), "+s"(s1), "+s"(s2), "+s"(s3),        \
                          "+s"(s4), "+s"(s5), "+s"(s6), "+s"(s7));       \
        a0 = fmaf(s0, uq[2 * (g) + 0][0], a0);                           \
        a1 = fmaf(s1, uq[2 * (g) + 0][1], a1);                           \
        a2 = fmaf(s2, uq[2 * (g) + 0][2], a2);                           \
        a3 = fmaf(s3, uq[2 * (g) + 0][3], a3);                           \
        a0 = fmaf(s4, uq[2 * (g) + 1][0], a0);                           \
        a1 = fmaf(s5, uq[2 * (g) + 1][1], a1);                           \
        a2 = fmaf(s6, uq[2 * (g) + 1][2], a2);                           \
        a3 = fmaf(s7, uq[2 * (g) + 1][3], a3);                           \
    }

    // one recurrence step: grouped hazard-free broadcast + pinned-reg U
    #define RNN_STEP(tokv, xwv)                                          \
    {                                                                    \
        float a0 = (xwv), a1 = 0.f, a2 = 0.f, a3 = 0.f;                  \
        DOT_GROUP(0) DOT_GROUP(1) DOT_GROUP(2) DOT_GROUP(3)              \
        DOT_GROUP(4) DOT_GROUP(5) DOT_GROUP(6) DOT_GROUP(7)              \
        float x2 = (a0 + a1) + (a2 + a3);                                \
        float ef = __builtin_amdgcn_exp2f(x2);                           \
        float r = __builtin_amdgcn_rcpf(ef + 1.f);                       \
        float hn = fmaf(-2.f, r, 1.f);                                   \
        h = ((tokv) != 0) ? hn : h;                                      \
        pooled += h;                                                     \
    }

    for (int t = 0; t < T_; t += 2) {
        // in-loop pin: any uq spill would force an in-loop reload.
        asm volatile("" :: "v"(uq[0]), "v"(uq[1]), "v"(uq[2]), "v"(uq[3]),
                           "v"(uq[4]), "v"(uq[5]), "v"(uq[6]), "v"(uq[7]),
                           "v"(uq[8]), "v"(uq[9]), "v"(uq[10]), "v"(uq[11]),
                           "v"(uq[12]), "v"(uq[13]), "v"(uq[14]), "v"(uq[15]));

        // prefetch steps t+2, t+3 (pad makes the tail read safe: EW[0])
        int2 tkB = *(const int2*)&sh_tok[t + 2];
        float xw2 = EW[tkB.x * H_ + j];
        float xw3 = EW[tkB.y * H_ + j];

        RNN_STEP(tkA.x, xw0);
        RNN_STEP(tkA.y, xw1);

        tkA = tkB;
        xw0 = xw2;
        xw1 = xw3;
    }
    #undef RNN_STEP
    #undef DOT_GROUP

    // ---- epilogue: pooled mean -> dense(2) -> sigmoid ----
    float p = pooled * (1.0f / (float)T_);
    float v0 = p * Wd[j * C_ + 0];
    float v1 = p * Wd[j * C_ + 1];
    #pragma unroll
    for (int off = 32; off >= 1; off >>= 1) {
        v0 += __shfl_down(v0, off, 64);
        v1 += __shfl_down(v1, off, 64);
    }
    if (j == 0) {
        float l0 = v0 + bd[0];
        float l1 = v1 + bd[1];
        out[b * C_ + 0] = 1.f / (1.f + __expf(-l0));
        out[b * C_ + 1] = 1.f / (1.f + __expf(-l1));
    }
}

// ---------------------------------------------------------------------------
extern "C" void kernel_launch(void* const* d_in, const int* in_sizes, int n_in,
                              void* d_out, int out_size, void* d_ws, size_t ws_size,
                              hipStream_t stream) {
    const int*   tokens = (const int*)  d_in[0];  // [B,T] int32
    const float* E      = (const float*)d_in[1];  // [V,D]
    const float* W      = (const float*)d_in[2];  // [D,H]
    const float* U      = (const float*)d_in[3];  // [H,H]
    const float* bias   = (const float*)d_in[4];  // [H]
    const float* Wd     = (const float*)d_in[5];  // [H,C]
    const float* bd     = (const float*)d_in[6];  // [C]
    float* out = (float*)d_out;                   // [B,C]
    float* EW  = (float*)d_ws;                    // [V,H] scratch: 1.28 MB

    ew_kernel<<<(V_ * H_ + 255) / 256, 256, 0, stream>>>(E, W, bias, EW);
    rnn_kernel<<<B_, H_, 0, stream>>>(tokens, EW, U, Wd, bd, out);
}